// Round 14
// baseline (154.905 us; speedup 1.0000x reference)
//
#include <hip/hip_runtime.h>
#include <stdint.h>

// Problem constants
#define D_  1024
#define S_  2048
#define B_  2
#define H_  16
#define DH_ 64
#define M_  (B_*S_)   // 4096 rows total

typedef __bf16 bf16x8 __attribute__((ext_vector_type(8)));
typedef float  f32x4  __attribute__((ext_vector_type(4)));
typedef float  f32x16 __attribute__((ext_vector_type(16)));
typedef short  short8 __attribute__((ext_vector_type(8)));
typedef unsigned uint4v __attribute__((ext_vector_type(4)));
typedef unsigned short u16;

static __device__ __forceinline__ u16 f2bf(float f){
  union { float f; unsigned u; } v; v.f = f;
  unsigned r = v.u + 0x7FFF + ((v.u >> 16) & 1);   // RNE
  return (u16)(r >> 16);
}
static __device__ __forceinline__ f32x4 mfma16(short8 a, short8 b, f32x4 c){
  return __builtin_amdgcn_mfma_f32_16x16x32_bf16(
      __builtin_bit_cast(bf16x8, a), __builtin_bit_cast(bf16x8, b), c, 0, 0, 0);
}
static __device__ __forceinline__ f32x16 mfma32(short8 a, short8 b, f32x16 c){
  return __builtin_amdgcn_mfma_f32_32x32x16_bf16(
      __builtin_bit_cast(bf16x8, a), __builtin_bit_cast(bf16x8, b), c, 0, 0, 0);
}
static __device__ __forceinline__ f32x16 zero16(){
  f32x16 z = {0,0,0,0,0,0,0,0,0,0,0,0,0,0,0,0};
  return z;
}
static __device__ __forceinline__ float fexp2(float x){
#if __has_builtin(__builtin_amdgcn_exp2f)
  return __builtin_amdgcn_exp2f(x);
#else
  return __exp2f(x);
#endif
}
static __device__ __forceinline__ unsigned cvtpk(float lo, float hi){
  unsigned r;
  asm("v_cvt_pk_bf16_f32 %0, %1, %2" : "=v"(r) : "v"(lo), "v"(hi));
  return r;
}
static __device__ __forceinline__ void gl_lds16(const u16* g, u16* lds){
  __builtin_amdgcn_global_load_lds(
      (const __attribute__((address_space(1))) void*)(uintptr_t)g,
      (__attribute__((address_space(3))) void*)(uintptr_t)lds, 16, 0, 0);
}

// ---------- fused prep: converts + ctx@Wc + mask-check, one launch ----------
// blocks [0,4096)      : x f32->bf16 (1M x4 groups)
// blocks [4096,8192)   : Wq/Wk/Wv/Wo f32->bf16 (4 x 256K x4 groups)
// blocks [8192,10240)  : mask all-ones check (writes 0 to flags on failure)
// block  10240         : cvec = context @ Wc
// flags pre-set nonzero via hipMemsetAsync before this kernel.
__global__ __launch_bounds__(256) void k_prep(
    const float* __restrict__ x, const float* __restrict__ Wq,
    const float* __restrict__ Wk, const float* __restrict__ Wv,
    const float* __restrict__ Wo,
    u16* __restrict__ xb, u16* __restrict__ wqb, u16* __restrict__ wkb,
    u16* __restrict__ wvb, u16* __restrict__ wob,
    const float* __restrict__ ctx, const float* __restrict__ Wc,
    float* __restrict__ cvec, const uint4* __restrict__ mask16,
    int* __restrict__ flags){
  const int bid = blockIdx.x;
  if(bid < 4096){
    int i = bid*256 + threadIdx.x;
    float4 v = ((const float4*)x)[i];
    ushort4 o; o.x = f2bf(v.x); o.y = f2bf(v.y); o.z = f2bf(v.z); o.w = f2bf(v.w);
    ((ushort4*)xb)[i] = o;
  } else if(bid < 8192){
    const int wsel = (bid - 4096) >> 10;
    const int i = ((bid - 4096) & 1023)*256 + threadIdx.x;
    const float* in; u16* out;
    switch(wsel){
      case 0: in = Wq; out = wqb; break;
      case 1: in = Wk; out = wkb; break;
      case 2: in = Wv; out = wvb; break;
      default: in = Wo; out = wob; break;
    }
    float4 v = ((const float4*)in)[i];
    ushort4 o; o.x = f2bf(v.x); o.y = f2bf(v.y); o.z = f2bf(v.z); o.w = f2bf(v.w);
    ((ushort4*)out)[i] = o;
  } else if(bid < 10240){
    int i = (bid - 8192)*256 + threadIdx.x;
    uint4 v = mask16[i];
    bool ok8  = (v.x==0x01010101u)&&(v.y==0x01010101u)&&(v.z==0x01010101u)&&(v.w==0x01010101u);
    bool ok32 = (v.x==1u)&&(v.y==1u)&&(v.z==1u)&&(v.w==1u);
    unsigned long long b8  = __ballot(!ok8);
    unsigned long long b32 = __ballot(!ok32);
    if((threadIdx.x & 63) == 0){
      if(b8 && b32) flags[0] = 0;   // neither byte- nor int-mask all-ones
    }
  } else {
    __shared__ float partial[2][2][64];
    int t = threadIdx.x;
    int half = t >> 7;           // 0..1 (512-d chunk)
    int b = (t >> 6) & 1;
    int j = t & 63;
    float s = 0.f;
    #pragma unroll 8
    for(int d = half*512; d < half*512 + 512; ++d)
      s += ctx[b*D_ + d] * Wc[d*DH_ + j];
    partial[half][b][j] = s;
    __syncthreads();
    if(t < 128){
      int b2 = t >> 6, j2 = t & 63;
      cvec[b2*DH_ + j2] = partial[0][b2][j2] + partial[1][b2][j2];
    }
  }
}

// ---------- fused QKV GEMM: 128x128 tile over Wcat (3072 cols) ----------
// bn 0..7  : Q  -> Qb (bf16) + qc reduction
// bn 8..15 : K  -> Kb (bf16, (K - beta*prev)*LOG2E/8) + kc reduction (pre-sub)
// bn 16..23: V  -> VT (bf16 transposed [b*1024+d][s])
__global__ __launch_bounds__(256,2) void k_gemm_qkv(const u16* __restrict__ A,
    const u16* __restrict__ Wcat, u16* __restrict__ Qb, u16* __restrict__ Kb,
    u16* __restrict__ VT, const float* __restrict__ cvec,
    const float* __restrict__ prev, const float* __restrict__ beta_p,
    float* __restrict__ qcb, float* __restrict__ kcb){
  __shared__ u16 As[128*64];   // 16 KB
  __shared__ u16 Bs[128*64];   // 16 KB
  __shared__ float red[2][2][64];
  const int tid = threadIdx.x;
  const int w = tid >> 6, l = tid & 63;
  const int wr = w >> 1, wc = w & 1;
  const int id = blockIdx.x;
  const int bn = id >> 5;       // 24 col-blocks (same-A blocks colocate on XCD)
  const int bm = id & 31;       // 32 row-blocks
  const int lr = l & 15, lh = l >> 4;
  const int srow = l >> 3, scol = (l & 7) * 8;

  f32x4 acc[4][4] = {};

  for(int kt = 0; kt < 16; ++kt){
    const int k0 = kt * 64;
    #pragma unroll
    for(int i = 0; i < 4; ++i){
      const int chunk = i*4 + w;
      gl_lds16(A    + (size_t)(bm*128 + chunk*8 + srow)*D_ + k0 + scol, &As[chunk*512]);
      gl_lds16(Wcat + (size_t)(bn*128 + chunk*8 + srow)*D_ + k0 + scol, &Bs[chunk*512]);
    }
    __syncthreads();
    #pragma unroll
    for(int kk = 0; kk < 2; ++kk){
      short8 a[4], b[4];
      #pragma unroll
      for(int m = 0; m < 4; ++m)
        a[m] = *(const short8*)&As[(wr*64 + m*16 + lr)*64 + kk*32 + lh*8];
      #pragma unroll
      for(int n = 0; n < 4; ++n)
        b[n] = *(const short8*)&Bs[(wc*64 + n*16 + lr)*64 + kk*32 + lh*8];
      #pragma unroll
      for(int m = 0; m < 4; ++m)
        #pragma unroll
        for(int n = 0; n < 4; ++n)
          acc[m][n] = mfma16(a[m], b[n], acc[m][n]);
    }
    __syncthreads();
  }

  const int b = bm >> 4;

  if(bn < 16){
    // qc/kc: wave's 64 cols = one head (head = (bn&7)*2 + wc)
    float cv[4];
    #pragma unroll
    for(int n = 0; n < 4; ++n) cv[n] = cvec[b*DH_ + n*16 + lr];
    float part[4][4];
    #pragma unroll
    for(int m = 0; m < 4; ++m)
      #pragma unroll
      for(int r = 0; r < 4; ++r){
        float p = acc[m][0][r]*cv[0] + acc[m][1][r]*cv[1]
                + acc[m][2][r]*cv[2] + acc[m][3][r]*cv[3];
        p += __shfl_xor(p, 1, 64); p += __shfl_xor(p, 2, 64);
        p += __shfl_xor(p, 4, 64); p += __shfl_xor(p, 8, 64);
        part[m][r] = p;
      }
    if(lr == 0){
      #pragma unroll
      for(int m = 0; m < 4; ++m)
        #pragma unroll
        for(int r = 0; r < 4; ++r)
          red[wr][wc][m*16 + lh*4 + r] = part[m][r];
    }
    __syncthreads();
    {
      int wr2 = tid >> 7, wc2 = (tid >> 6) & 1, i = tid & 63;
      int s = (bm & 15)*128 + wr2*64 + i;
      int head = (bn & 7)*2 + wc2;
      float* qkc = (bn < 8) ? qcb : kcb;
      qkc[((size_t)b*H_ + head)*S_ + s] = red[wr2][wc2][i];
    }
  }

  if(bn < 8){
    #pragma unroll
    for(int m = 0; m < 4; ++m){
      const size_t row0 = (size_t)bm*128 + wr*64 + m*16 + lh*4;
      #pragma unroll
      for(int n = 0; n < 4; ++n){
        const size_t col = (size_t)bn*128 + wc*64 + n*16 + lr;
        #pragma unroll
        for(int r = 0; r < 4; ++r)
          Qb[(row0 + r)*D_ + col] = f2bf(acc[m][n][r]);
      }
    }
  } else if(bn < 16){
    const float beta = beta_p[0];
    const float KSCALE = 0.125f * 1.44269504088896340736f;
    #pragma unroll
    for(int m = 0; m < 4; ++m){
      const size_t row0 = (size_t)bm*128 + wr*64 + m*16 + lh*4;
      #pragma unroll
      for(int n = 0; n < 4; ++n){
        const size_t col = (size_t)(bn - 8)*128 + wc*64 + n*16 + lr;
        #pragma unroll
        for(int r = 0; r < 4; ++r){
          float v = (acc[m][n][r] - beta * prev[(row0 + r)*D_ + n*16 + lr]) * KSCALE;
          Kb[(row0 + r)*D_ + col] = f2bf(v);
        }
      }
    }
  } else {
    #pragma unroll
    for(int m = 0; m < 4; ++m){
      const int s0 = (bm & 15)*128 + wr*64 + m*16 + lh*4;
      #pragma unroll
      for(int n = 0; n < 4; ++n){
        const int col = (bn - 16)*128 + wc*64 + n*16 + lr;
        ushort4 o;
        o.x = f2bf(acc[m][n][0]); o.y = f2bf(acc[m][n][1]);
        o.z = f2bf(acc[m][n][2]); o.w = f2bf(acc[m][n][3]);
        *(ushort4*)&VT[((size_t)(b*1024 + col))*S_ + s0] = o;
      }
    }
  }
}

// ---------- O GEMM: 128x64 tile, f32 out ----------
__global__ __launch_bounds__(256,2) void k_gemm_o(const u16* __restrict__ A,
    const u16* __restrict__ W, float* __restrict__ Cout){
  __shared__ u16 As[128*64];   // 16 KB
  __shared__ u16 Bs[64*64];    //  8 KB
  const int tid = threadIdx.x;
  const int w = tid >> 6, l = tid & 63;
  const int wr = w >> 1, wc = w & 1;
  const int bm = blockIdx.x >> 4;
  const int bn = blockIdx.x & 15;
  const int lr = l & 15, lh = l >> 4;
  const int srow = l >> 3, scol = (l & 7) * 8;

  f32x4 acc[4][2] = {};

  for(int kt = 0; kt < 16; ++kt){
    const int k0 = kt * 64;
    #pragma unroll
    for(int i = 0; i < 4; ++i){
      const int chunk = i*4 + w;
      gl_lds16(A + (size_t)(bm*128 + chunk*8 + srow)*D_ + k0 + scol, &As[chunk*512]);
    }
    #pragma unroll
    for(int i = 0; i < 2; ++i){
      const int chunk = w*2 + i;
      gl_lds16(W + (size_t)(bn*64 + chunk*8 + srow)*D_ + k0 + scol, &Bs[chunk*512]);
    }
    __syncthreads();
    #pragma unroll
    for(int kk = 0; kk < 2; ++kk){
      short8 a[4], b[2];
      #pragma unroll
      for(int m = 0; m < 4; ++m)
        a[m] = *(const short8*)&As[(wr*64 + m*16 + lr)*64 + kk*32 + lh*8];
      #pragma unroll
      for(int n = 0; n < 2; ++n)
        b[n] = *(const short8*)&Bs[(wc*32 + n*16 + lr)*64 + kk*32 + lh*8];
      #pragma unroll
      for(int m = 0; m < 4; ++m)
        #pragma unroll
        for(int n = 0; n < 2; ++n)
          acc[m][n] = mfma16(a[m], b[n], acc[m][n]);
    }
    __syncthreads();
  }
  #pragma unroll
  for(int m = 0; m < 4; ++m){
    const size_t row0 = (size_t)bm*128 + wr*64 + m*16 + lh*4;
    #pragma unroll
    for(int n = 0; n < 2; ++n){
      const size_t col = (size_t)bn*64 + wc*32 + n*16 + lr;
      #pragma unroll
      for(int r = 0; r < 4; ++r)
        Cout[(row0 + r)*D_ + col] = acc[m][n][r];
    }
  }
}

// ---------- flash attention (round-8 version, byte-identical) ----------
// 1024 blocks (2 waves x 32 q-rows), bh = id&31 (XCD-pinned), qb = id>>5.
// S^T = mfma32(K, Q): lane owns one q (l&31) x 32 keys -> lane-local softmax,
// scalar denominator. P->bf16 via v_cvt_pk_bf16_f32, hi/lo half exchange via
// v_permlane32_swap_b32. O^T = mfma32(V^T, P^T). No P LDS traffic.
__global__ __launch_bounds__(128,2) void k_attn(const u16* __restrict__ Qb,
    const u16* __restrict__ Kb, const u16* __restrict__ VT,
    const float* __restrict__ qc, const float* __restrict__ kc,
    const float* __restrict__ alpha_p, const unsigned char* __restrict__ mask,
    const int* __restrict__ flags, u16* __restrict__ Ob){
  __shared__ u16 Kbuf[2][4096];   // [64 keys][64 dh] XOR-swizzled rows
  __shared__ u16 Vbuf[2][4096];   // [64 d][64 keys] XOR-swizzled rows
  const int tid = threadIdx.x;
  const int wv = tid >> 6, l = tid & 63;
  const int q32 = l & 31, hi = l >> 5, hb = hi*8;
  const int id = blockIdx.x;
  const int bh = id & 31, qb = id >> 5;
  const int b = bh >> 4, h = bh & 15;
  const int q0w = qb*64 + wv*32;
  const float aL = alpha_p[0] * (1.0f/64.0f) * 1.44269504088896340736f;
  const bool allones = flags[0] != 0;
  const u16* Kb_h = Kb + (size_t)b*S_*D_ + h*DH_;
  const u16* VT_h = VT + ((size_t)(b*1024 + h*DH_))*S_;
  const float* kcp = kc + (size_t)bh*S_;
  const unsigned char* maskr = mask + ((size_t)b*S_ + q0w + q32)*S_;

  const int srow = l >> 3;
  const int sdh  = ((l & 7) ^ srow) * 8;
  #define STAGEK(TILE, BUF) { _Pragma("unroll") for(int j = 0; j < 4; ++j){      \
      const int ck = j*2 + wv;                                                   \
      gl_lds16(Kb_h + (size_t)((TILE)*64 + ck*8 + srow)*D_ + sdh,                \
               &Kbuf[BUF][ck*512]); } }
  #define STAGEV(TILE, BUF) { _Pragma("unroll") for(int j = 0; j < 4; ++j){      \
      const int ck = j*2 + wv;                                                   \
      gl_lds16(VT_h + (size_t)(ck*8 + srow)*S_ + (TILE)*64 + sdh,                \
               &Vbuf[BUF][ck*512]); } }

  short8 qa[4];
  #pragma unroll
  for(int c = 0; c < 4; ++c)
    qa[c] = *(const short8*)&Qb[((size_t)b*S_ + q0w + q32)*D_ + h*DH_ + c*16 + hb];
  const float aq = aL * qc[(size_t)bh*S_ + q0w + q32];

  f32x16 oacc[2] = {zero16(), zero16()};
  float lp = 0.f;
  const int xk = (q32 & 7) << 3;

  STAGEK(0, 0);
  STAGEV(0, 0);
  __syncthreads();

  for(int kt = 0; kt < 32; ++kt){
    const int buf = kt & 1;
    const int k0 = kt*64;
    const int tn = (kt+1) & 31;
    STAGEK(tn, buf^1);
    STAGEV(tn, buf^1);

    f32x16 sacc[2] = {zero16(), zero16()};
    #pragma unroll
    for(int kg = 0; kg < 2; ++kg)
      #pragma unroll
      for(int c = 0; c < 4; ++c){
        short8 kf = *(const short8*)&Kbuf[buf][(kg*32 + q32)*64 + ((c*16 + hb) ^ xk)];
        sacc[kg] = mfma32(kf, qa[c], sacc[kg]);
      }
    short8 vf[2][4];
    #pragma unroll
    for(int dh2 = 0; dh2 < 2; ++dh2)
      #pragma unroll
      for(int c = 0; c < 4; ++c)
        vf[dh2][c] = *(const short8*)&Vbuf[buf][(dh2*32 + q32)*64 + ((c*16 + hb) ^ xk)];

    unsigned pk[2][8];
    #pragma unroll
    for(int kg = 0; kg < 2; ++kg){
      float p[16];
      #pragma unroll
      for(int rg = 0; rg < 4; ++rg){
        f32x4 kv = *(const f32x4*)&kcp[k0 + kg*32 + rg*8 + hi*4];
        unsigned mu = 0x01010101u;
        if(!allones) mu = *(const unsigned*)&maskr[k0 + kg*32 + rg*8 + hi*4];
        #pragma unroll
        for(int j = 0; j < 4; ++j){
          float t = sacc[kg][rg*4 + j] + aq*kv[j];
          if(((mu >> (8*j)) & 255u) == 0u) t = -160.0f;
          float e = fexp2(t);
          lp += e;
          p[rg*4 + j] = e;
        }
      }
      #pragma unroll
      for(int i = 0; i < 8; ++i) pk[kg][i] = cvtpk(p[2*i], p[2*i+1]);
    }

    #pragma unroll
    for(int c = 0; c < 4; ++c){
      const int kg = c >> 1, c4 = (c & 1)*4;
      unsigned x0 = pk[kg][c4+0], y0 = pk[kg][c4+2];
      unsigned x1 = pk[kg][c4+1], y1 = pk[kg][c4+3];
      asm("v_permlane32_swap_b32 %0, %1" : "+v"(x0), "+v"(y0));
      asm("v_permlane32_swap_b32 %0, %1" : "+v"(x1), "+v"(y1));
      uint4v pb = {x0, x1, y0, y1};
      short8 pbf = __builtin_bit_cast(short8, pb);
      #pragma unroll
      for(int dh2 = 0; dh2 < 2; ++dh2)
        oacc[dh2] = mfma32(vf[dh2][c], pbf, oacc[dh2]);
    }
    __syncthreads();
  }
  #undef STAGEK
  #undef STAGEV

  float lt = lp + __shfl_xor(lp, 32, 64);
  float inv = 1.0f / lt;
  u16* orow = Ob + ((size_t)b*S_ + q0w + q32)*D_ + h*DH_;
  #pragma unroll
  for(int dh2 = 0; dh2 < 2; ++dh2)
    #pragma unroll
    for(int rg = 0; rg < 4; ++rg){
      ushort4 o;
      o.x = f2bf(oacc[dh2][rg*4+0]*inv);
      o.y = f2bf(oacc[dh2][rg*4+1]*inv);
      o.z = f2bf(oacc[dh2][rg*4+2]*inv);
      o.w = f2bf(oacc[dh2][rg*4+3]*inv);
      *(ushort4*)&orow[dh2*32 + rg*8 + hi*4] = o;
    }
}

// ---------------------------------------------------------------------------
extern "C" void kernel_launch(void* const* d_in, const int* in_sizes, int n_in,
                              void* d_out, int out_size, void* d_ws, size_t ws_size,
                              hipStream_t stream){
  const float* x    = (const float*)d_in[0];
  const float* ctx  = (const float*)d_in[1];
  const float* prev = (const float*)d_in[2];
  const unsigned char* mask = (const unsigned char*)d_in[3];
  const float* Wq = (const float*)d_in[4];
  const float* Wk = (const float*)d_in[5];
  const float* Wv = (const float*)d_in[6];
  const float* Wo = (const float*)d_in[7];
  const float* Wc = (const float*)d_in[8];
  const float* alpha = (const float*)d_in[9];
  const float* beta  = (const float*)d_in[10];

  char* ws = (char*)d_ws;
  size_t off = 0;
  auto alloc = [&](size_t bytes)->void*{
    void* p = ws + off; off += (bytes + 255) & ~(size_t)255; return p;
  };
  u16* xb   = (u16*)alloc((size_t)M_*D_*2);       // reused as Ob after QKV GEMM
  u16* wcat = (u16*)alloc((size_t)3*D_*D_*2);     // Wq|Wk|Wv stacked
  u16* wob  = (u16*)alloc((size_t)D_*D_*2);
  u16* Qb   = (u16*)alloc((size_t)M_*D_*2);
  u16* Kb   = (u16*)alloc((size_t)M_*D_*2);
  u16* VT   = (u16*)alloc((size_t)B_*D_*S_*2);    // V transposed: [b*1024+d][s]
  float* qcb  = (float*)alloc((size_t)B_*H_*S_*4);
  float* kcb  = (float*)alloc((size_t)B_*H_*S_*4);
  float* cvec = (float*)alloc(512);
  int*  flags = (int*)alloc(64);
  u16* Ob = xb;

  // flags := nonzero (0x01010101); prep's mask blocks clear to 0 on failure
  hipMemsetAsync(flags, 1, 8, stream);
  k_prep<<<10241, 256, 0, stream>>>(x, Wq, Wk, Wv, Wo,
      xb, wcat, wcat + (size_t)D_*D_, wcat + (size_t)2*D_*D_, wob,
      ctx, Wc, cvec, (const uint4*)mask, flags);
  k_gemm_qkv<<<768, 256, 0, stream>>>(xb, wcat, Qb, Kb, VT, cvec, prev, beta, qcb, kcb);
  k_attn<<<1024, 128, 0, stream>>>(Qb, Kb, VT, qcb, kcb, alpha, mask, flags, Ob);
  k_gemm_o<<<512, 256, 0, stream>>>(Ob, wob, (float*)d_out);
}

// Round 16
// 147.368 us; speedup vs baseline: 1.0511x; 1.0511x over previous
//
#include <hip/hip_runtime.h>
#include <stdint.h>

// Problem constants
#define D_  1024
#define S_  2048
#define B_  2
#define H_  16
#define DH_ 64
#define M_  (B_*S_)   // 4096 rows total

typedef __bf16 bf16x8 __attribute__((ext_vector_type(8)));
typedef float  f32x4  __attribute__((ext_vector_type(4)));
typedef float  f32x16 __attribute__((ext_vector_type(16)));
typedef short  short8 __attribute__((ext_vector_type(8)));
typedef unsigned uint4v __attribute__((ext_vector_type(4)));
typedef unsigned short u16;

static __device__ __forceinline__ u16 f2bf(float f){
  union { float f; unsigned u; } v; v.f = f;
  unsigned r = v.u + 0x7FFF + ((v.u >> 16) & 1);   // RNE
  return (u16)(r >> 16);
}
static __device__ __forceinline__ f32x4 mfma16(short8 a, short8 b, f32x4 c){
  return __builtin_amdgcn_mfma_f32_16x16x32_bf16(
      __builtin_bit_cast(bf16x8, a), __builtin_bit_cast(bf16x8, b), c, 0, 0, 0);
}
static __device__ __forceinline__ f32x16 mfma32(short8 a, short8 b, f32x16 c){
  return __builtin_amdgcn_mfma_f32_32x32x16_bf16(
      __builtin_bit_cast(bf16x8, a), __builtin_bit_cast(bf16x8, b), c, 0, 0, 0);
}
static __device__ __forceinline__ f32x16 zero16(){
  f32x16 z = {0,0,0,0,0,0,0,0,0,0,0,0,0,0,0,0};
  return z;
}
static __device__ __forceinline__ float fexp2(float x){
#if __has_builtin(__builtin_amdgcn_exp2f)
  return __builtin_amdgcn_exp2f(x);
#else
  return __exp2f(x);
#endif
}
static __device__ __forceinline__ unsigned cvtpk(float lo, float hi){
  unsigned r;
  asm("v_cvt_pk_bf16_f32 %0, %1, %2" : "=v"(r) : "v"(lo), "v"(hi));
  return r;
}
static __device__ __forceinline__ void gl_lds16(const u16* g, u16* lds){
  __builtin_amdgcn_global_load_lds(
      (const __attribute__((address_space(1))) void*)(uintptr_t)g,
      (__attribute__((address_space(3))) void*)(uintptr_t)lds, 16, 0, 0);
}

// ---------- f32 -> bf16 convert ----------
__global__ void k_f2bf(const float* __restrict__ in, u16* __restrict__ out, int n4){
  int i = blockIdx.x * blockDim.x + threadIdx.x;
  if(i >= n4) return;
  float4 v = ((const float4*)in)[i];
  ushort4 o; o.x = f2bf(v.x); o.y = f2bf(v.y); o.z = f2bf(v.z); o.w = f2bf(v.w);
  ((ushort4*)out)[i] = o;
}

__global__ void k_f2bf4(const float* __restrict__ a0, const float* __restrict__ a1,
                        const float* __restrict__ a2, const float* __restrict__ a3,
                        u16* __restrict__ o0, u16* __restrict__ o1,
                        u16* __restrict__ o2, u16* __restrict__ o3, int n4){
  const float* in; u16* out;
  switch(blockIdx.y){
    case 0: in=a0; out=o0; break;
    case 1: in=a1; out=o1; break;
    case 2: in=a2; out=o2; break;
    default: in=a3; out=o3; break;
  }
  int i = blockIdx.x * blockDim.x + threadIdx.x;
  if(i >= n4) return;
  float4 v = ((const float4*)in)[i];
  ushort4 o; o.x = f2bf(v.x); o.y = f2bf(v.y); o.z = f2bf(v.z); o.w = f2bf(v.w);
  ((ushort4*)out)[i] = o;
}

// ---------- c = context @ Wc (B x 64), also init flags ----------
__global__ void k_ctx(const float* __restrict__ context, const float* __restrict__ Wc,
                      float* __restrict__ cvec, int* __restrict__ flags){
  __shared__ float partial[4][2][64];
  int t = threadIdx.x;            // 512 threads
  if(t < 2) flags[t] = 1;
  int c = t >> 7;                 // d-chunk 0..3
  int b = (t >> 6) & 1;
  int j = t & 63;
  float s = 0.f;
  #pragma unroll 8
  for(int d = c*256; d < (c+1)*256; ++d) s += context[b*D_ + d] * Wc[d*DH_ + j];
  partial[c][b][j] = s;
  __syncthreads();
  if(t < 128){
    int b2 = t >> 6, j2 = t & 63;
    cvec[b2*DH_ + j2] = partial[0][b2][j2] + partial[1][b2][j2]
                      + partial[2][b2][j2] + partial[3][b2][j2];
  }
}

// ---------- mask all-ones check ----------
__global__ void k_mask_check(const uint4* __restrict__ m, int n16, int* flags){
  int i = blockIdx.x * blockDim.x + threadIdx.x;
  bool ok8 = true, ok32 = true;
  if(i < n16){
    uint4 v = m[i];
    ok8  = (v.x==0x01010101u)&&(v.y==0x01010101u)&&(v.z==0x01010101u)&&(v.w==0x01010101u);
    ok32 = (v.x==1u)&&(v.y==1u)&&(v.z==1u)&&(v.w==1u);
  }
  unsigned long long b8  = __ballot(!ok8);
  unsigned long long b32 = __ballot(!ok32);
  if((threadIdx.x & 63) == 0){
    if(b8)  flags[0] = 0;   // benign race: all writers write 0
    if(b32) flags[1] = 0;
  }
}

// ---------- fused QKV GEMM: 128x128 tile over Wcat (3072 cols) ----------
// bn 0..7  : Q  -> Qb (bf16) + qc reduction
// bn 8..15 : K  -> Kb (bf16, (K - beta*prev)*LOG2E/8) + kc reduction (pre-sub)
// bn 16..23: V  -> VT (bf16 transposed [b*1024+d][s])
__global__ __launch_bounds__(256,2) void k_gemm_qkv(const u16* __restrict__ A,
    const u16* __restrict__ Wcat, u16* __restrict__ Qb, u16* __restrict__ Kb,
    u16* __restrict__ VT, const float* __restrict__ cvec,
    const float* __restrict__ prev, const float* __restrict__ beta_p,
    float* __restrict__ qcb, float* __restrict__ kcb){
  __shared__ u16 As[128*64];   // 16 KB
  __shared__ u16 Bs[128*64];   // 16 KB
  __shared__ float red[2][2][64];
  const int tid = threadIdx.x;
  const int w = tid >> 6, l = tid & 63;
  const int wr = w >> 1, wc = w & 1;
  const int id = blockIdx.x;
  const int bn = id >> 5;       // 24 col-blocks (same-A blocks colocate on XCD)
  const int bm = id & 31;       // 32 row-blocks
  const int lr = l & 15, lh = l >> 4;
  const int srow = l >> 3, scol = (l & 7) * 8;

  f32x4 acc[4][4] = {};

  for(int kt = 0; kt < 16; ++kt){
    const int k0 = kt * 64;
    #pragma unroll
    for(int i = 0; i < 4; ++i){
      const int chunk = i*4 + w;
      gl_lds16(A    + (size_t)(bm*128 + chunk*8 + srow)*D_ + k0 + scol, &As[chunk*512]);
      gl_lds16(Wcat + (size_t)(bn*128 + chunk*8 + srow)*D_ + k0 + scol, &Bs[chunk*512]);
    }
    __syncthreads();
    #pragma unroll
    for(int kk = 0; kk < 2; ++kk){
      short8 a[4], b[4];
      #pragma unroll
      for(int m = 0; m < 4; ++m)
        a[m] = *(const short8*)&As[(wr*64 + m*16 + lr)*64 + kk*32 + lh*8];
      #pragma unroll
      for(int n = 0; n < 4; ++n)
        b[n] = *(const short8*)&Bs[(wc*64 + n*16 + lr)*64 + kk*32 + lh*8];
      #pragma unroll
      for(int m = 0; m < 4; ++m)
        #pragma unroll
        for(int n = 0; n < 4; ++n)
          acc[m][n] = mfma16(a[m], b[n], acc[m][n]);
    }
    __syncthreads();
  }

  const int b = bm >> 4;

  if(bn < 16){
    // qc/kc: wave's 64 cols = one head (head = (bn&7)*2 + wc)
    float cv[4];
    #pragma unroll
    for(int n = 0; n < 4; ++n) cv[n] = cvec[b*DH_ + n*16 + lr];
    float part[4][4];
    #pragma unroll
    for(int m = 0; m < 4; ++m)
      #pragma unroll
      for(int r = 0; r < 4; ++r){
        float p = acc[m][0][r]*cv[0] + acc[m][1][r]*cv[1]
                + acc[m][2][r]*cv[2] + acc[m][3][r]*cv[3];
        p += __shfl_xor(p, 1, 64); p += __shfl_xor(p, 2, 64);
        p += __shfl_xor(p, 4, 64); p += __shfl_xor(p, 8, 64);
        part[m][r] = p;
      }
    if(lr == 0){
      #pragma unroll
      for(int m = 0; m < 4; ++m)
        #pragma unroll
        for(int r = 0; r < 4; ++r)
          red[wr][wc][m*16 + lh*4 + r] = part[m][r];
    }
    __syncthreads();
    {
      int wr2 = tid >> 7, wc2 = (tid >> 6) & 1, i = tid & 63;
      int s = (bm & 15)*128 + wr2*64 + i;
      int head = (bn & 7)*2 + wc2;
      float* qkc = (bn < 8) ? qcb : kcb;
      qkc[((size_t)b*H_ + head)*S_ + s] = red[wr2][wc2][i];
    }
  }

  if(bn < 8){
    #pragma unroll
    for(int m = 0; m < 4; ++m){
      const size_t row0 = (size_t)bm*128 + wr*64 + m*16 + lh*4;
      #pragma unroll
      for(int n = 0; n < 4; ++n){
        const size_t col = (size_t)bn*128 + wc*64 + n*16 + lr;
        #pragma unroll
        for(int r = 0; r < 4; ++r)
          Qb[(row0 + r)*D_ + col] = f2bf(acc[m][n][r]);
      }
    }
  } else if(bn < 16){
    const float beta = beta_p[0];
    const float KSCALE = 0.125f * 1.44269504088896340736f;
    #pragma unroll
    for(int m = 0; m < 4; ++m){
      const size_t row0 = (size_t)bm*128 + wr*64 + m*16 + lh*4;
      #pragma unroll
      for(int n = 0; n < 4; ++n){
        const size_t col = (size_t)(bn - 8)*128 + wc*64 + n*16 + lr;
        #pragma unroll
        for(int r = 0; r < 4; ++r){
          float v = (acc[m][n][r] - beta * prev[(row0 + r)*D_ + n*16 + lr]) * KSCALE;
          Kb[(row0 + r)*D_ + col] = f2bf(v);
        }
      }
    }
  } else {
    #pragma unroll
    for(int m = 0; m < 4; ++m){
      const int s0 = (bm & 15)*128 + wr*64 + m*16 + lh*4;
      #pragma unroll
      for(int n = 0; n < 4; ++n){
        const int col = (bn - 16)*128 + wc*64 + n*16 + lr;
        ushort4 o;
        o.x = f2bf(acc[m][n][0]); o.y = f2bf(acc[m][n][1]);
        o.z = f2bf(acc[m][n][2]); o.w = f2bf(acc[m][n][3]);
        *(ushort4*)&VT[((size_t)(b*1024 + col))*S_ + s0] = o;
      }
    }
  }
}

// ---------- O GEMM: 128x64 tile, f32 out ----------
__global__ __launch_bounds__(256,2) void k_gemm_o(const u16* __restrict__ A,
    const u16* __restrict__ W, float* __restrict__ Cout){
  __shared__ u16 As[128*64];   // 16 KB
  __shared__ u16 Bs[64*64];    //  8 KB
  const int tid = threadIdx.x;
  const int w = tid >> 6, l = tid & 63;
  const int wr = w >> 1, wc = w & 1;
  const int bm = blockIdx.x >> 4;
  const int bn = blockIdx.x & 15;
  const int lr = l & 15, lh = l >> 4;
  const int srow = l >> 3, scol = (l & 7) * 8;

  f32x4 acc[4][2] = {};

  for(int kt = 0; kt < 16; ++kt){
    const int k0 = kt * 64;
    #pragma unroll
    for(int i = 0; i < 4; ++i){
      const int chunk = i*4 + w;
      gl_lds16(A + (size_t)(bm*128 + chunk*8 + srow)*D_ + k0 + scol, &As[chunk*512]);
    }
    #pragma unroll
    for(int i = 0; i < 2; ++i){
      const int chunk = w*2 + i;
      gl_lds16(W + (size_t)(bn*64 + chunk*8 + srow)*D_ + k0 + scol, &Bs[chunk*512]);
    }
    __syncthreads();
    #pragma unroll
    for(int kk = 0; kk < 2; ++kk){
      short8 a[4], b[2];
      #pragma unroll
      for(int m = 0; m < 4; ++m)
        a[m] = *(const short8*)&As[(wr*64 + m*16 + lr)*64 + kk*32 + lh*8];
      #pragma unroll
      for(int n = 0; n < 2; ++n)
        b[n] = *(const short8*)&Bs[(wc*32 + n*16 + lr)*64 + kk*32 + lh*8];
      #pragma unroll
      for(int m = 0; m < 4; ++m)
        #pragma unroll
        for(int n = 0; n < 2; ++n)
          acc[m][n] = mfma16(a[m], b[n], acc[m][n]);
    }
    __syncthreads();
  }
  #pragma unroll
  for(int m = 0; m < 4; ++m){
    const size_t row0 = (size_t)bm*128 + wr*64 + m*16 + lh*4;
    #pragma unroll
    for(int n = 0; n < 2; ++n){
      const size_t col = (size_t)bn*64 + wc*32 + n*16 + lr;
      #pragma unroll
      for(int r = 0; r < 4; ++r)
        Cout[(row0 + r)*D_ + col] = acc[m][n][r];
    }
  }
}

// ---------- flash attention (round-8 version, byte-identical) ----------
// 1024 blocks (2 waves x 32 q-rows), bh = id&31 (XCD-pinned), qb = id>>5.
// S^T = mfma32(K, Q): lane owns one q (l&31) x 32 keys -> lane-local softmax,
// scalar denominator. P->bf16 via v_cvt_pk_bf16_f32, hi/lo half exchange via
// v_permlane32_swap_b32. O^T = mfma32(V^T, P^T). No P LDS traffic.
__global__ __launch_bounds__(128,2) void k_attn(const u16* __restrict__ Qb,
    const u16* __restrict__ Kb, const u16* __restrict__ VT,
    const float* __restrict__ qc, const float* __restrict__ kc,
    const float* __restrict__ alpha_p, const unsigned char* __restrict__ mask,
    const int* __restrict__ flags, u16* __restrict__ Ob){
  __shared__ u16 Kbuf[2][4096];   // [64 keys][64 dh] XOR-swizzled rows
  __shared__ u16 Vbuf[2][4096];   // [64 d][64 keys] XOR-swizzled rows
  const int tid = threadIdx.x;
  const int wv = tid >> 6, l = tid & 63;
  const int q32 = l & 31, hi = l >> 5, hb = hi*8;
  const int id = blockIdx.x;
  const int bh = id & 31, qb = id >> 5;
  const int b = bh >> 4, h = bh & 15;
  const int q0w = qb*64 + wv*32;
  const float aL = alpha_p[0] * (1.0f/64.0f) * 1.44269504088896340736f;
  const bool allones = (flags[0] | flags[1]) != 0;
  const u16* Kb_h = Kb + (size_t)b*S_*D_ + h*DH_;
  const u16* VT_h = VT + ((size_t)(b*1024 + h*DH_))*S_;
  const float* kcp = kc + (size_t)bh*S_;
  const unsigned char* maskr = mask + ((size_t)b*S_ + q0w + q32)*S_;

  const int srow = l >> 3;
  const int sdh  = ((l & 7) ^ srow) * 8;
  #define STAGEK(TILE, BUF) { _Pragma("unroll") for(int j = 0; j < 4; ++j){      \
      const int ck = j*2 + wv;                                                   \
      gl_lds16(Kb_h + (size_t)((TILE)*64 + ck*8 + srow)*D_ + sdh,                \
               &Kbuf[BUF][ck*512]); } }
  #define STAGEV(TILE, BUF) { _Pragma("unroll") for(int j = 0; j < 4; ++j){      \
      const int ck = j*2 + wv;                                                   \
      gl_lds16(VT_h + (size_t)(ck*8 + srow)*S_ + (TILE)*64 + sdh,                \
               &Vbuf[BUF][ck*512]); } }

  short8 qa[4];
  #pragma unroll
  for(int c = 0; c < 4; ++c)
    qa[c] = *(const short8*)&Qb[((size_t)b*S_ + q0w + q32)*D_ + h*DH_ + c*16 + hb];
  const float aq = aL * qc[(size_t)bh*S_ + q0w + q32];

  f32x16 oacc[2] = {zero16(), zero16()};
  float lp = 0.f;
  const int xk = (q32 & 7) << 3;

  STAGEK(0, 0);
  STAGEV(0, 0);
  __syncthreads();

  for(int kt = 0; kt < 32; ++kt){
    const int buf = kt & 1;
    const int k0 = kt*64;
    const int tn = (kt+1) & 31;
    STAGEK(tn, buf^1);
    STAGEV(tn, buf^1);

    f32x16 sacc[2] = {zero16(), zero16()};
    #pragma unroll
    for(int kg = 0; kg < 2; ++kg)
      #pragma unroll
      for(int c = 0; c < 4; ++c){
        short8 kf = *(const short8*)&Kbuf[buf][(kg*32 + q32)*64 + ((c*16 + hb) ^ xk)];
        sacc[kg] = mfma32(kf, qa[c], sacc[kg]);
      }
    short8 vf[2][4];
    #pragma unroll
    for(int dh2 = 0; dh2 < 2; ++dh2)
      #pragma unroll
      for(int c = 0; c < 4; ++c)
        vf[dh2][c] = *(const short8*)&Vbuf[buf][(dh2*32 + q32)*64 + ((c*16 + hb) ^ xk)];

    unsigned pk[2][8];
    #pragma unroll
    for(int kg = 0; kg < 2; ++kg){
      float p[16];
      #pragma unroll
      for(int rg = 0; rg < 4; ++rg){
        f32x4 kv = *(const f32x4*)&kcp[k0 + kg*32 + rg*8 + hi*4];
        unsigned mu = 0x01010101u;
        if(!allones) mu = *(const unsigned*)&maskr[k0 + kg*32 + rg*8 + hi*4];
        #pragma unroll
        for(int j = 0; j < 4; ++j){
          float t = sacc[kg][rg*4 + j] + aq*kv[j];
          if(((mu >> (8*j)) & 255u) == 0u) t = -160.0f;
          float e = fexp2(t);
          lp += e;
          p[rg*4 + j] = e;
        }
      }
      #pragma unroll
      for(int i = 0; i < 8; ++i) pk[kg][i] = cvtpk(p[2*i], p[2*i+1]);
    }

    #pragma unroll
    for(int c = 0; c < 4; ++c){
      const int kg = c >> 1, c4 = (c & 1)*4;
      unsigned x0 = pk[kg][c4+0], y0 = pk[kg][c4+2];
      unsigned x1 = pk[kg][c4+1], y1 = pk[kg][c4+3];
      asm("v_permlane32_swap_b32 %0, %1" : "+v"(x0), "+v"(y0));
      asm("v_permlane32_swap_b32 %0, %1" : "+v"(x1), "+v"(y1));
      uint4v pb = {x0, x1, y0, y1};
      short8 pbf = __builtin_bit_cast(short8, pb);
      #pragma unroll
      for(int dh2 = 0; dh2 < 2; ++dh2)
        oacc[dh2] = mfma32(vf[dh2][c], pbf, oacc[dh2]);
    }
    __syncthreads();
  }
  #undef STAGEK
  #undef STAGEV

  float lt = lp + __shfl_xor(lp, 32, 64);
  float inv = 1.0f / lt;
  u16* orow = Ob + ((size_t)b*S_ + q0w + q32)*D_ + h*DH_;
  #pragma unroll
  for(int dh2 = 0; dh2 < 2; ++dh2)
    #pragma unroll
    for(int rg = 0; rg < 4; ++rg){
      ushort4 o;
      o.x = f2bf(oacc[dh2][rg*4+0]*inv);
      o.y = f2bf(oacc[dh2][rg*4+1]*inv);
      o.z = f2bf(oacc[dh2][rg*4+2]*inv);
      o.w = f2bf(oacc[dh2][rg*4+3]*inv);
      *(ushort4*)&orow[dh2*32 + rg*8 + hi*4] = o;
    }
}

// ---------------------------------------------------------------------------
extern "C" void kernel_launch(void* const* d_in, const int* in_sizes, int n_in,
                              void* d_out, int out_size, void* d_ws, size_t ws_size,
                              hipStream_t stream){
  const float* x    = (const float*)d_in[0];
  const float* ctx  = (const float*)d_in[1];
  const float* prev = (const float*)d_in[2];
  const unsigned char* mask = (const unsigned char*)d_in[3];
  const float* Wq = (const float*)d_in[4];
  const float* Wk = (const float*)d_in[5];
  const float* Wv = (const float*)d_in[6];
  const float* Wo = (const float*)d_in[7];
  const float* Wc = (const float*)d_in[8];
  const float* alpha = (const float*)d_in[9];
  const float* beta  = (const float*)d_in[10];

  char* ws = (char*)d_ws;
  size_t off = 0;
  auto alloc = [&](size_t bytes)->void*{
    void* p = ws + off; off += (bytes + 255) & ~(size_t)255; return p;
  };
  u16* xb   = (u16*)alloc((size_t)M_*D_*2);       // reused as Ob after QKV GEMM
  u16* wcat = (u16*)alloc((size_t)3*D_*D_*2);     // Wq|Wk|Wv stacked
  u16* wob  = (u16*)alloc((size_t)D_*D_*2);
  u16* Qb   = (u16*)alloc((size_t)M_*D_*2);
  u16* Kb   = (u16*)alloc((size_t)M_*D_*2);
  u16* VT   = (u16*)alloc((size_t)B_*D_*S_*2);    // V transposed: [b*1024+d][s]
  float* qcb  = (float*)alloc((size_t)B_*H_*S_*4);
  float* kcb  = (float*)alloc((size_t)B_*H_*S_*4);
  float* cvec = (float*)alloc(512);
  int*  flags = (int*)alloc(64);
  u16* Ob = xb;

  k_f2bf<<<M_*D_/4/256, 256, 0, stream>>>(x, xb, M_*D_/4);
  {
    dim3 g(D_*D_/4/256, 4);
    k_f2bf4<<<g, 256, 0, stream>>>(Wq, Wk, Wv, Wo,
        wcat, wcat + (size_t)D_*D_, wcat + (size_t)2*D_*D_, wob, D_*D_/4);
  }
  k_ctx<<<1, 512, 0, stream>>>(ctx, Wc, cvec, flags);
  {
    int n16 = B_*S_*S_/16;
    k_mask_check<<<n16/256, 256, 0, stream>>>((const uint4*)mask, n16, flags);
  }
  k_gemm_qkv<<<768, 256, 0, stream>>>(xb, wcat, Qb, Kb, VT, cvec, prev, beta, qcb, kcb);
  k_attn<<<1024, 128, 0, stream>>>(Qb, Kb, VT, qcb, kcb, alpha, mask, flags, Ob);
  k_gemm_o<<<512, 256, 0, stream>>>(Ob, wob, (float*)d_out);
}